// Round 4
// baseline (759.656 us; speedup 1.0000x reference)
//
#include <hip/hip_runtime.h>
#include <hip/hip_bf16.h>

#define KREM 172
#define NDIM 11008        // 172 * 64
#define JPAD 176          // 11 * 16
#define KP_HAD 192        // padded K for hadB (6 * 32)
#define KP_Y 192          // padded K stride for swizzled Y^T in LDS (24 KB)

typedef __bf16 bf16x8 __attribute__((ext_vector_type(8)));
typedef float  f32x4  __attribute__((ext_vector_type(4)));
typedef float  f32x2  __attribute__((ext_vector_type(2)));

// had (172x172 fp32) -> hadB (176x192 bf16, zero padded), row-major,
// PRE-SCALED by 1/sqrt(11008) so stage 1 needs no per-element scale mul.
__global__ void prep_had_kernel(const float* __restrict__ had,
                                __bf16* __restrict__ hadB) {
  int idx = blockIdx.x * 256 + threadIdx.x;
  if (idx >= JPAD * KP_HAD) return;
  int j = idx / KP_HAD;
  int k = idx - j * KP_HAD;
  float v = (j < KREM && k < KREM) ? had[j * KREM + k] * 9.53115434e-3f : 0.0f;
  hadB[idx] = (__bf16)v;
}

// Occupancy: LDS 24 KB/block -> 5 blocks/CU fits 120/160 KB; (256,5) caps
// VGPRs at 102 so residency is 5 blocks (20 waves/CU, was 4/16).
__global__ void __launch_bounds__(256, 5) had_fused_kernel(
    const float* __restrict__ x, const __bf16* __restrict__ hadB,
    float* __restrict__ out) {
  // Swizzled Y^T: element (n,k) at
  //   Yt[n*KP_Y + ((k>>3) ^ (n>>3) ^ (n&7))*8 + (k&7)]
  // e = (n>>3)^(n&7) only alters the low 3 bits of kb = k>>3 (kb in [0,24)),
  // so kb^e stays in [0,24) and KP_Y=192 is closed under the swizzle.
  // Reads: 8 contiguous lanes (8 rows, same k-column) hit 8 distinct 16-B
  // slots = all 32 banks. Writes: (c0^lid^i) spans 8 col-groups x 4 banks,
  // 2 lanes/bank share a dword (byte-merge). Both conflict-free.
  __shared__ __bf16 Yt[64 * KP_Y];

  const int tid  = threadIdx.x;
  const int wave = tid >> 6;
  const int lane = tid & 63;
  const size_t rowoff = (size_t)blockIdx.x * NDIM;
  const float* xr   = x + rowoff;
  float*       outr = out + rowoff;

  // Zero ONLY the k-pad slots (logical k in [172,192)). These physical slots
  // are address-disjoint from every stage-1 write, so no barrier is needed
  // between this and stage 1 — the single pre-stage-2 barrier covers both.
  if (tid < 64) {
    const int e = (tid >> 3) ^ (tid & 7);   // swizzle term for row n = tid
    __bf16* row = Yt + tid * KP_Y;
    const f32x4 z4 = {0.f, 0.f, 0.f, 0.f};
    *(f32x4*)(row + (((22 ^ e) << 3)))     = z4;              // k 176..183
    *(f32x4*)(row + (((23 ^ e) << 3)))     = z4;              // k 184..191
    *(f32x2*)(row + (((21 ^ e) << 3)) + 4) = (f32x2){0.f, 0.f}; // k 172..175
  }

  // ---------------- Stage 1: FHT-64 per segment, fp32, on-load ----------------
  const int grp = tid >> 3;  // 0..31  (segment within pass)
  const int lid = tid & 7;   // lane within 8-lane segment group

  // unroll 3: 6 float4 loads in flight (~48 VGPRs) instead of 12 (~96) —
  // keeps peak register pressure under the 102-VGPR cap for 5 blocks/CU.
#pragma unroll 3
  for (int p = 0; p < 6; ++p) {
    const int k = p * 32 + grp;
    if (k < KREM) {
      const float4* seg = (const float4*)(xr + k * 64 + lid * 8);
      float4 a = seg[0], b = seg[1];
      float v[8] = {a.x, a.y, a.z, a.w, b.x, b.y, b.z, b.w};
      // in-register butterfly stages (m-strides 1,2,4)
#pragma unroll
      for (int s = 1; s <= 4; s <<= 1) {
#pragma unroll
        for (int i = 0; i < 8; ++i) {
          if ((i & s) == 0) {
            float u0 = v[i], u1 = v[i + s];
            v[i] = u0 + u1;
            v[i + s] = u0 - u1;
          }
        }
      }
      // cross-lane stages (m-strides 8,16,32 -> lane masks 1,2,4)
      // v_new = t + sgn*v  (one FMA per element; sgn = +/-1 exact)
#pragma unroll
      for (int s = 1; s <= 4; s <<= 1) {
        const float sgn = (lid & s) ? -1.0f : 1.0f;
#pragma unroll
        for (int i = 0; i < 8; ++i) {
          float t = __shfl_xor(v[i], s, 64);
          v[i] = __builtin_fmaf(v[i], sgn, t);
        }
      }
      // write transposed + swizzled bf16 (scale already folded into hadB)
      const int ko  = k & 7;
      const int kbl = (k >> 3) ^ lid;    // n>>3 == lid
#pragma unroll
      for (int i = 0; i < 8; ++i) {      // n&7 == i
        Yt[(lid * 8 + i) * KP_Y + (((kbl ^ i) << 3)) + ko] = (__bf16)v[i];
      }
    }
  }
  __syncthreads();

  // ---------------- Stage 2: Z^T = Y^T(64x192) @ had^T(192x176) via MFMA ------
  // Sequential j-tiles: acc[4] live (16 VGPRs) instead of acc[3][4] (48).
  const int l15 = lane & 15;
  const int q   = lane >> 4;
  const int njt = (wave < 3) ? 3 : 2;  // waves own jt = {w, w+4, w+8} (<11)

#pragma unroll 1
  for (int jl = 0; jl < njt; ++jl) {
    const int jt   = wave + jl * 4;
    const int jrow = jt * 16 + l15;
    const __bf16* hb = hadB + jrow * KP_HAD;
    f32x4 acc[4] = {};
    __builtin_amdgcn_s_setprio(1);
#pragma unroll
    for (int kc = 0; kc < 6; ++kc) {
      const int kbase = kc * 32 + q * 8;
      const bf16x8 bfr = *(const bf16x8*)&hb[kbase];
#pragma unroll
      for (int nt = 0; nt < 4; ++nt) {
        const int n  = nt * 16 + l15;
        const int kb = (kbase >> 3) ^ (n >> 3) ^ (n & 7);
        const bf16x8 afr = *(const bf16x8*)&Yt[n * KP_Y + (kb << 3)];
        acc[nt] = __builtin_amdgcn_mfma_f32_16x16x32_bf16(afr, bfr, acc[nt],
                                                          0, 0, 0);
      }
    }
    __builtin_amdgcn_s_setprio(0);
    // epilogue: D[row=n=q*4+reg][col=j=l15] -> out[j*64 + n], contiguous float4
    if (jrow < KREM) {
#pragma unroll
      for (int nt = 0; nt < 4; ++nt) {
        *(f32x4*)(outr + jrow * 64 + nt * 16 + q * 4) = acc[nt];
      }
    }
  }
}

extern "C" void kernel_launch(void* const* d_in, const int* in_sizes, int n_in,
                              void* d_out, int out_size, void* d_ws, size_t ws_size,
                              hipStream_t stream) {
  const float* x   = (const float*)d_in[0];
  const float* had = (const float*)d_in[1];
  __bf16* hadB = (__bf16*)d_ws;                   // 176*192*2 = 67584 B
  float* out = (float*)d_out;
  const int rows = in_sizes[0] / NDIM;            // 8192

  hipLaunchKernelGGL(prep_had_kernel, dim3((JPAD * KP_HAD + 255) / 256),
                     dim3(256), 0, stream, had, hadB);
  hipLaunchKernelGGL(had_fused_kernel, dim3(rows), dim3(256), 0, stream,
                     x, hadB, out);
}

// Round 5
// 594.010 us; speedup vs baseline: 1.2789x; 1.2789x over previous
//
#include <hip/hip_runtime.h>
#include <hip/hip_bf16.h>

#define KREM 172
#define NDIM 11008        // 172 * 64
#define JPAD 176          // 11 * 16
#define KP_HAD 192        // padded K for hadB (6 * 32)
#define KP_Y 192          // padded K stride for swizzled Y^T in LDS (24 KB)

typedef __bf16 bf16x8 __attribute__((ext_vector_type(8)));
typedef float  f32x4  __attribute__((ext_vector_type(4)));
typedef float  f32x2  __attribute__((ext_vector_type(2)));

// had (172x172 fp32) -> hadB (176x192 bf16, zero padded), row-major,
// PRE-SCALED by 1/sqrt(11008) so stage 1 needs no per-element scale mul.
__global__ void prep_had_kernel(const float* __restrict__ had,
                                __bf16* __restrict__ hadB) {
  int idx = blockIdx.x * 256 + threadIdx.x;
  if (idx >= JPAD * KP_HAD) return;
  int j = idx / KP_HAD;
  int k = idx - j * KP_HAD;
  float v = (j < KREM && k < KREM) ? had[j * KREM + k] * 9.53115434e-3f : 0.0f;
  hadB[idx] = (__bf16)v;
}

__global__ void __launch_bounds__(256, 4) had_fused_kernel(
    const float* __restrict__ x, const __bf16* __restrict__ hadB,
    float* __restrict__ out) {
  // Swizzled Y^T: element (n,k) at
  //   Yt[n*KP_Y + ((k>>3) ^ (n>>3) ^ (n&7))*8 + (k&7)]
  // (bijective within 24 column-groups; read- and write-conflict-free.)
  __shared__ __bf16 Yt[64 * KP_Y];   // 24 KB
  // Z staging for coalesced output: one 64-row x 64-float j-band (16 KB),
  // XOR-swizzled chunk index so stage-writes/drain-reads are bank-balanced.
  __shared__ float Zs[64 * 64];      // 16 KB  (total 40 KB -> 4 blocks/CU)

  const int tid  = threadIdx.x;
  const int wave = tid >> 6;
  const int lane = tid & 63;
  const size_t rowoff = (size_t)blockIdx.x * NDIM;
  const float* xr   = x + rowoff;
  float*       outr = out + rowoff;

  // Zero ONLY the k-pad slots (logical k in [172,192)). Address-disjoint from
  // every stage-1 write, so the single pre-stage-2 barrier covers both.
  if (tid < 64) {
    const int e = (tid >> 3) ^ (tid & 7);   // swizzle term for row n = tid
    __bf16* row = Yt + tid * KP_Y;
    const f32x4 z4 = {0.f, 0.f, 0.f, 0.f};
    *(f32x4*)(row + (((22 ^ e) << 3)))     = z4;              // k 176..183
    *(f32x4*)(row + (((23 ^ e) << 3)))     = z4;              // k 184..191
    *(f32x2*)(row + (((21 ^ e) << 3)) + 4) = (f32x2){0.f, 0.f}; // k 172..175
  }

  // ---------------- Stage 1: FHT-64 per segment, fp32, on-load ----------------
  const int grp = tid >> 3;  // 0..31  (segment within pass)
  const int lid = tid & 7;   // lane within 8-lane segment group

  // Full unroll: keep ~12 float4 loads in flight (R4 showed unroll-3 + low
  // VGPR cap collapses MLP to 3.2 TB/s).
#pragma unroll
  for (int p = 0; p < 6; ++p) {
    const int k = p * 32 + grp;
    if (k < KREM) {
      const float4* seg = (const float4*)(xr + k * 64 + lid * 8);
      float4 a = seg[0], b = seg[1];
      float v[8] = {a.x, a.y, a.z, a.w, b.x, b.y, b.z, b.w};
      // in-register butterfly stages (m-strides 1,2,4)
#pragma unroll
      for (int s = 1; s <= 4; s <<= 1) {
#pragma unroll
        for (int i = 0; i < 8; ++i) {
          if ((i & s) == 0) {
            float u0 = v[i], u1 = v[i + s];
            v[i] = u0 + u1;
            v[i + s] = u0 - u1;
          }
        }
      }
      // cross-lane stages (m-strides 8,16,32 -> lane masks 1,2,4)
#pragma unroll
      for (int s = 1; s <= 4; s <<= 1) {
        const float sgn = (lid & s) ? -1.0f : 1.0f;
#pragma unroll
        for (int i = 0; i < 8; ++i) {
          float t = __shfl_xor(v[i], s, 64);
          v[i] = __builtin_fmaf(v[i], sgn, t);
        }
      }
      // write transposed + swizzled bf16 (scale already folded into hadB)
      const int ko  = k & 7;
      const int kbl = (k >> 3) ^ lid;    // n>>3 == lid
#pragma unroll
      for (int i = 0; i < 8; ++i) {      // n&7 == i
        Yt[(lid * 8 + i) * KP_Y + (((kbl ^ i) << 3)) + ko] = (__bf16)v[i];
      }
    }
  }
  __syncthreads();

  // ---------------- Stage 2: Z^T = Y^T(64x192) @ had^T(192x176) via MFMA ------
  // All 4 waves compute one contiguous j-band per jl (jt = jl*4 + wave),
  // stage D-fragments into Zs, then drain Zs as fully-contiguous 4-KB wave
  // stores. This replaces the old scattered 16-B/lane @ 256-B-stride stores
  // that caused 1.74x write + 1.41x fetch HBM amplification (R4 counters).
  const int l15 = lane & 15;
  const int q   = lane >> 4;

  for (int jl = 0; jl < 3; ++jl) {
    const int jt = jl * 4 + wave;        // contiguous band: j in [jl*64, jl*64+64)
    if (jt < 11) {
      const int jrow = jt * 16 + l15;
      const __bf16* hb = hadB + jrow * KP_HAD;
      f32x4 acc[4] = {};
      __builtin_amdgcn_s_setprio(1);
#pragma unroll
      for (int kc = 0; kc < 6; ++kc) {
        const int kbase = kc * 32 + q * 8;
        const bf16x8 bfr = *(const bf16x8*)&hb[kbase];
#pragma unroll
        for (int nt = 0; nt < 4; ++nt) {
          const int n  = nt * 16 + l15;
          const int kb = (kbase >> 3) ^ (n >> 3) ^ (n & 7);
          const bf16x8 afr = *(const bf16x8*)&Yt[n * KP_Y + (kb << 3)];
          acc[nt] = __builtin_amdgcn_mfma_f32_16x16x32_bf16(afr, bfr, acc[nt],
                                                            0, 0, 0);
        }
      }
      __builtin_amdgcn_s_setprio(0);
      // stage: lane holds D[n = nt*16+q*4+0..3][j = jrow]; Zs row r = j-jl*64,
      // 16-B chunk cq = nt*4+q, stored at cq ^ (r&7) (bank-balanced).
      const int r = wave * 16 + l15;
#pragma unroll
      for (int nt = 0; nt < 4; ++nt) {
        const int cq = (nt * 4 + q) ^ (r & 7);
        *(f32x4*)&Zs[r * 64 + cq * 4] = acc[nt];
      }
    }
    __syncthreads();   // Zs band complete (uniform across waves)
    // drain: 4 x 4-KB fully-contiguous wave stores; skip j >= 172 at jl=2.
    const int lim = (jl < 2) ? 1024 : 704;   // valid 16-B chunks in this band
#pragma unroll
    for (int i = 0; i < 4; ++i) {
      const int e16 = i * 256 + tid;         // 16-B chunk index in band
      if (e16 < lim) {
        const int r  = e16 >> 4;
        const int cq = (e16 & 15) ^ (r & 7);
        *(f32x4*)(outr + jl * 4096 + e16 * 4) = *(const f32x4*)&Zs[r * 64 + cq * 4];
      }
    }
    __syncthreads();   // protect Zs before next band's stage-writes
  }
}

extern "C" void kernel_launch(void* const* d_in, const int* in_sizes, int n_in,
                              void* d_out, int out_size, void* d_ws, size_t ws_size,
                              hipStream_t stream) {
  const float* x   = (const float*)d_in[0];
  const float* had = (const float*)d_in[1];
  __bf16* hadB = (__bf16*)d_ws;                   // 176*192*2 = 67584 B
  float* out = (float*)d_out;
  const int rows = in_sizes[0] / NDIM;            // 8192

  hipLaunchKernelGGL(prep_had_kernel, dim3((JPAD * KP_HAD + 255) / 256),
                     dim3(256), 0, stream, had, hadB);
  hipLaunchKernelGGL(had_fused_kernel, dim3(rows), dim3(256), 0, stream,
                     x, hadB, out);
}